// Round 1
// baseline (365.042 us; speedup 1.0000x reference)
//
#include <hip/hip_runtime.h>

// TurboQuantEmbedding: V=128000, D=1024, BW=4, GS=256, G=4, PACK=2, PD=512
// out[token, g*256 + e] = FWHT_256(codebook[nibble(token, g, :)])[e] * sign[g][e] * norm[token,g] / 256
// (folds /sqrt(GS)=16 from dequant and /sqrt(GS)=16 from fwht normalization)

#define NGROUP 4
#define GSIZE  256

struct SignBits { unsigned w[NGROUP][GSIZE / 32]; };

// Replicate np.random.RandomState(42 + g*256).choice([-1,1], size=256):
// legacy randint(0,2) with rng=1 draws ONE tempered MT19937 32-bit output per
// sample (32-bit masked-rejection path, mask=1, always accepted);
// idx = draw & 1; sign = idx ? +1 : -1. Seeding = standard init_genrand.
constexpr SignBits gen_sign_bits() {
    SignBits S{};
    for (int g = 0; g < NGROUP; ++g) {
        unsigned mt[624] = {};
        unsigned s = 42u + (unsigned)g * 256u;
        for (int i = 0; i < 624; ++i) {
            mt[i] = s;
            s = 1812433253u * (s ^ (s >> 30)) + (unsigned)(i + 1);
        }
        // one in-place twist (generates 624 raw outputs; we use first 256)
        for (int i = 0; i < 624; ++i) {
            unsigned y = (mt[i] & 0x80000000u) | (mt[(i + 1) % 624] & 0x7fffffffu);
            mt[i] = mt[(i + 397) % 624] ^ (y >> 1) ^ ((y & 1u) ? 0x9908b0dfu : 0u);
        }
        for (int e = 0; e < GSIZE; ++e) {
            unsigned y = mt[e];
            y ^= y >> 11;
            y ^= (y << 7) & 0x9d2c5680u;
            y ^= (y << 15) & 0xefc60000u;
            y ^= y >> 18;
            if (y & 1u) S.w[g][e >> 5] |= (1u << (e & 31));  // bit=1 -> sign +1
        }
    }
    return S;
}

__constant__ SignBits c_sign = gen_sign_bits();

__global__ __launch_bounds__(256) void turboquant_kernel(
    const int*   __restrict__ input_ids,      // (n_tokens,)
    const int*   __restrict__ indices_packed, // (V, 512) each word holds a byte = 2 nibbles
    const float* __restrict__ weight_norms,   // (V, 4)
    const float* __restrict__ codebook,       // (16,)
    float*       __restrict__ out)            // (n_tokens, 1024)
{
    const int token = blockIdx.x;
    const int tid   = threadIdx.x;
    const int g     = tid >> 6;   // wave id = group
    const int l     = tid & 63;   // lane

    const int id = input_ids[token];

    // lane l holds codebook[l & 15]; lookup via wave shuffle (ds_bpermute)
    const float cbv = codebook[l & 15];

    // lane l loads packed words 2l, 2l+1 of this group's 128-word slice
    // -> elements e = 4l .. 4l+3 of the 256-element group
    const int2 pw = *(const int2*)(indices_packed + (size_t)id * 512 + g * 128 + 2 * l);

    const int n0 =  pw.x        & 15;  // pos 4l   (even -> low nibble)
    const int n1 = (pw.x >> 4)  & 15;  // pos 4l+1 (odd  -> high nibble)
    const int n2 =  pw.y        & 15;  // pos 4l+2
    const int n3 = (pw.y >> 4)  & 15;  // pos 4l+3

    float y0 = __shfl(cbv, n0);
    float y1 = __shfl(cbv, n1);
    float y2 = __shfl(cbv, n2);
    float y3 = __shfl(cbv, n3);

    // FWHT-256 over element index e = 4l + k
    // stage h=1 (bit 0 of e -> in-register)
    float a, b;
    a = y0 + y1; b = y0 - y1; y0 = a; y1 = b;
    a = y2 + y3; b = y2 - y3; y2 = a; y3 = b;
    // stage h=2 (bit 1 of e -> in-register)
    a = y0 + y2; b = y0 - y2; y0 = a; y2 = b;
    a = y1 + y3; b = y1 - y3; y1 = a; y3 = b;
    // stages h=4..128 (bits 2..7 of e = bits 0..5 of lane -> shfl_xor)
#pragma unroll
    for (int m = 1; m <= 32; m <<= 1) {
        const float o0 = __shfl_xor(y0, m);
        const float o1 = __shfl_xor(y1, m);
        const float o2 = __shfl_xor(y2, m);
        const float o3 = __shfl_xor(y3, m);
        const bool up = (l & m) != 0;
        y0 = up ? (o0 - y0) : (y0 + o0);
        y1 = up ? (o1 - y1) : (y1 + o1);
        y2 = up ? (o2 - y2) : (y2 + o2);
        y3 = up ? (o3 - y3) : (y3 + o3);
    }

    const float norm  = weight_norms[(size_t)id * 4 + g];
    const float scale = norm * (1.0f / 256.0f);

    // sign bits for e = 4l..4l+3 live in word l>>3, bits 4*(l&7)..+3
    const unsigned w = c_sign.w[g][l >> 3];
    const int bb = (l & 7) * 4;
    const float s0 = ((w >> (bb + 0)) & 1u) ? scale : -scale;
    const float s1 = ((w >> (bb + 1)) & 1u) ? scale : -scale;
    const float s2 = ((w >> (bb + 2)) & 1u) ? scale : -scale;
    const float s3 = ((w >> (bb + 3)) & 1u) ? scale : -scale;

    float4 o;
    o.x = y0 * s0;
    o.y = y1 * s1;
    o.z = y2 * s2;
    o.w = y3 * s3;
    ((float4*)out)[(size_t)token * 256 + g * 64 + l] = o;
}

extern "C" void kernel_launch(void* const* d_in, const int* in_sizes, int n_in,
                              void* d_out, int out_size, void* d_ws, size_t ws_size,
                              hipStream_t stream) {
    const int*   input_ids      = (const int*)d_in[0];
    const int*   indices_packed = (const int*)d_in[1];
    const float* weight_norms   = (const float*)d_in[2];
    const float* codebook       = (const float*)d_in[3];
    float*       out            = (float*)d_out;

    const int n_tokens = in_sizes[0];  // 8 * 4096 = 32768

    turboquant_kernel<<<n_tokens, 256, 0, stream>>>(
        input_ids, indices_packed, weight_norms, codebook, out);
}

// Round 2
// 357.007 us; speedup vs baseline: 1.0225x; 1.0225x over previous
//
#include <hip/hip_runtime.h>

// TurboQuantEmbedding: V=128000, D=1024, BW=4, GS=256, G=4, PACK=2, PD=512
// out[token, 256g + e] = FWHT_256(codebook[nibbles])[e] * sign[g][e] * norm[token,g] / 256
// Wave = one token. Lane l: group g = l>>4, lane-digit i = l&15.
// Element map within group: e = 4*i + 64*m + k  (m,k in-register, i cross-lane).
// FWHT digits: h=1 fused into LDS LUT; h=2 in-reg (k); h=4..32 via shfl_xor on i;
// h=64,128 in-reg (m).

#define NGROUP 4

struct SignTbl { unsigned short u[NGROUP][16]; };  // bit j=4m+k set => sign NEGATIVE

// np.random.RandomState(42 + g*256).choice([-1,1], 256): one tempered MT19937
// 32-bit draw per sample; low bit 1 -> +1 (verified absmax=0 in R0).
// Here we set the table bit when the sign is NEGATIVE (low bit == 0).
constexpr SignTbl gen_sign_tbl() {
    SignTbl T{};
    for (int g = 0; g < NGROUP; ++g) {
        unsigned mt[624] = {};
        unsigned s = 42u + (unsigned)g * 256u;
        for (int i = 0; i < 624; ++i) {
            mt[i] = s;
            s = 1812433253u * (s ^ (s >> 30)) + (unsigned)(i + 1);
        }
        for (int i = 0; i < 624; ++i) {
            unsigned y = (mt[i] & 0x80000000u) | (mt[(i + 1) % 624] & 0x7fffffffu);
            mt[i] = mt[(i + 397) % 624] ^ (y >> 1) ^ ((y & 1u) ? 0x9908b0dfu : 0u);
        }
        unsigned neg[256] = {};
        for (int e = 0; e < 256; ++e) {
            unsigned y = mt[e];
            y ^= y >> 11;
            y ^= (y << 7) & 0x9d2c5680u;
            y ^= (y << 15) & 0xefc60000u;
            y ^= y >> 18;
            neg[e] = (y & 1u) ? 0u : 1u;  // bit==0 -> -1
        }
        for (int i = 0; i < 16; ++i)
            for (int m = 0; m < 4; ++m)
                for (int k = 0; k < 4; ++k)
                    if (neg[4 * i + 64 * m + k])
                        T.u[g][i] |= (unsigned short)(1u << (4 * m + k));
    }
    return T;
}

__constant__ SignTbl c_sign = gen_sign_tbl();

__global__ __launch_bounds__(256) void turboquant_kernel(
    const int*   __restrict__ input_ids,      // (n_tokens,)
    const int*   __restrict__ indices_packed, // (V, 512), one byte per int32
    const float* __restrict__ weight_norms,   // (V, 4)
    const float* __restrict__ codebook,       // (16,)
    float*       __restrict__ out,            // (n_tokens, 1024)
    int n_tokens)
{
    // byte -> (c[lo]+c[hi], c[lo]-c[hi]): fuses dequant + FWHT stage h=1
    __shared__ float2 lut[256];
    const int tid = threadIdx.x;
    {
        const float lo = codebook[tid & 15];
        const float hi = codebook[tid >> 4];
        lut[tid] = make_float2(lo + hi, lo - hi);
    }
    __syncthreads();

    const int token = blockIdx.x * 4 + (tid >> 6);
    if (token >= n_tokens) return;

    const int l = tid & 63;
    const int g = l >> 4;
    const int i = l & 15;

    const int id = input_ids[token];
    const int* row = indices_packed + (size_t)id * 512 + g * 128 + 2 * i;

    float v[4][4];  // [m][k-slot]
#pragma unroll
    for (int m = 0; m < 4; ++m) {
        const int2 w = *(const int2*)(row + 32 * m);  // words for e=4i+64m+{0..3}
        const float2 p0 = lut[w.x & 255];  // elements k=0 (low nib), k=1 (high)
        const float2 p1 = lut[w.y & 255];  // elements k=2, k=3
        // h=1 done by LUT; h=2 pairs (0,2) and (1,3):
        v[m][0] = p0.x + p1.x;
        v[m][2] = p0.x - p1.x;
        v[m][1] = p0.y + p1.y;
        v[m][3] = p0.y - p1.y;
    }

    // cross-lane stages h=4,8,16,32 -> xor masks 1,2,4,8 on lane-digit i
#pragma unroll
    for (int mask = 1; mask <= 8; mask <<= 1) {
        const unsigned sm = (i & mask) ? 0x80000000u : 0u;
#pragma unroll
        for (int m = 0; m < 4; ++m) {
#pragma unroll
            for (int k = 0; k < 4; ++k) {
                const float o = __shfl_xor(v[m][k], mask);
                v[m][k] = o + __uint_as_float(__float_as_uint(v[m][k]) ^ sm);
            }
        }
    }

    // in-register stages h=64 (m bit0), h=128 (m bit1)
#pragma unroll
    for (int k = 0; k < 4; ++k) {
        const float a = v[0][k], b = v[1][k], c = v[2][k], d = v[3][k];
        const float ab0 = a + b, ab1 = a - b, cd0 = c + d, cd1 = c - d;
        v[0][k] = ab0 + cd0;
        v[2][k] = ab0 - cd0;
        v[1][k] = ab1 + cd1;
        v[3][k] = ab1 - cd1;
    }

    const float    norm       = weight_norms[(size_t)id * 4 + g];
    const unsigned scale_bits = __float_as_uint(norm * (1.0f / 256.0f));  // norm>=0 -> bit31==0
    const unsigned u          = (unsigned)c_sign.u[g][i];                 // neg-flags, bit j=4m+k

    float* obase = out + (size_t)token * 1024 + g * 256 + 4 * i;
#pragma unroll
    for (int m = 0; m < 4; ++m) {
        float4 o;
        o.x = v[m][0] * __uint_as_float(((u << (31 - (4 * m + 0))) & 0x80000000u) ^ scale_bits);
        o.y = v[m][1] * __uint_as_float(((u << (31 - (4 * m + 1))) & 0x80000000u) ^ scale_bits);
        o.z = v[m][2] * __uint_as_float(((u << (31 - (4 * m + 2))) & 0x80000000u) ^ scale_bits);
        o.w = v[m][3] * __uint_as_float(((u << (31 - (4 * m + 3))) & 0x80000000u) ^ scale_bits);
        *(float4*)(obase + 64 * m) = o;  // 4x 256B dense segments per instr: coalesced
    }
}

extern "C" void kernel_launch(void* const* d_in, const int* in_sizes, int n_in,
                              void* d_out, int out_size, void* d_ws, size_t ws_size,
                              hipStream_t stream) {
    const int*   input_ids      = (const int*)d_in[0];
    const int*   indices_packed = (const int*)d_in[1];
    const float* weight_norms   = (const float*)d_in[2];
    const float* codebook       = (const float*)d_in[3];
    float*       out            = (float*)d_out;

    const int n_tokens = in_sizes[0];  // 8 * 4096 = 32768

    turboquant_kernel<<<(n_tokens + 3) / 4, 256, 0, stream>>>(
        input_ids, indices_packed, weight_norms, codebook, out, n_tokens);
}

// Round 3
// 355.071 us; speedup vs baseline: 1.0281x; 1.0055x over previous
//
#include <hip/hip_runtime.h>

// TurboQuantEmbedding: V=128000, D=1024, BW=4, GS=256, G=4, PACK=2, PD=512
// out[token, 256g + e] = FWHT_256(codebook[nibbles])[e] * sign[g][e] * norm[token,g] / 256
// Wave = one token. Lane l: group g = l>>4, lane-digit i = l&15.
// Element map within group: e = 4*i + 64*m + k  (m,k in-register, i cross-lane).
// FWHT digits: h=1 fused into LDS LUT; h=2 in-reg (k); h=4,8 via DPP quad_perm;
// h=16 via ds_swizzle (xor4); h=32 via DPP row_ror:8; h=64,128 in-reg (m).
// DPP moves 48 of 64 cross-lane butterflies off the LDS pipe onto the VALU.

#define NGROUP 4

struct SignTbl { unsigned short u[NGROUP][16]; };  // bit j=4m+k set => sign NEGATIVE

// np.random.RandomState(42 + g*256).choice([-1,1], 256): one tempered MT19937
// 32-bit draw per sample; low bit 1 -> +1 (verified absmax=0 in R1/R2).
constexpr SignTbl gen_sign_tbl() {
    SignTbl T{};
    for (int g = 0; g < NGROUP; ++g) {
        unsigned mt[624] = {};
        unsigned s = 42u + (unsigned)g * 256u;
        for (int i = 0; i < 624; ++i) {
            mt[i] = s;
            s = 1812433253u * (s ^ (s >> 30)) + (unsigned)(i + 1);
        }
        for (int i = 0; i < 624; ++i) {
            unsigned y = (mt[i] & 0x80000000u) | (mt[(i + 1) % 624] & 0x7fffffffu);
            mt[i] = mt[(i + 397) % 624] ^ (y >> 1) ^ ((y & 1u) ? 0x9908b0dfu : 0u);
        }
        unsigned neg[256] = {};
        for (int e = 0; e < 256; ++e) {
            unsigned y = mt[e];
            y ^= y >> 11;
            y ^= (y << 7) & 0x9d2c5680u;
            y ^= (y << 15) & 0xefc60000u;
            y ^= y >> 18;
            neg[e] = (y & 1u) ? 0u : 1u;  // low bit==0 -> -1
        }
        for (int i = 0; i < 16; ++i)
            for (int m = 0; m < 4; ++m)
                for (int k = 0; k < 4; ++k)
                    if (neg[4 * i + 64 * m + k])
                        T.u[g][i] |= (unsigned short)(1u << (4 * m + k));
    }
    return T;
}

__constant__ SignTbl c_sign = gen_sign_tbl();

// DPP butterfly: y' = dpp_swap(y) + ysign * y   (v_mov_b32_dpp + v_fma_f32)
#define DPP_QUAD_XOR1 0xB1   // quad_perm [1,0,3,2]  == lane xor 1
#define DPP_QUAD_XOR2 0x4E   // quad_perm [2,3,0,1]  == lane xor 2
#define DPP_ROW_ROR8  0x128  // row_ror:8 within row-16 == lane xor 8

template <int CTRL>
__device__ __forceinline__ float bfly_dpp(float y, float ysign) {
    int o = __builtin_amdgcn_update_dpp(0, __float_as_int(y), CTRL, 0xF, 0xF, true);
    return fmaf(ysign, y, __int_as_float(o));
}

__global__ __launch_bounds__(256) void turboquant_kernel(
    const int*   __restrict__ input_ids,      // (n_tokens,)
    const int*   __restrict__ indices_packed, // (V, 512), one byte per int32
    const float* __restrict__ weight_norms,   // (V, 4)
    const float* __restrict__ codebook,       // (16,)
    float*       __restrict__ out,            // (n_tokens, 1024)
    int n_tokens)
{
    // byte -> (c[lo]+c[hi], c[lo]-c[hi]): fuses dequant + FWHT stage h=1
    __shared__ float2 lut[256];
    const int tid = threadIdx.x;
    {
        const float lo = codebook[tid & 15];
        const float hi = codebook[tid >> 4];
        lut[tid] = make_float2(lo + hi, lo - hi);
    }
    __syncthreads();

    const int token = blockIdx.x * 4 + (tid >> 6);
    if (token >= n_tokens) return;

    const int l = tid & 63;
    const int g = l >> 4;
    const int i = l & 15;

    const int id = input_ids[token];
    const int* row = indices_packed + (size_t)id * 512 + g * 128 + 2 * i;

    // issue all 4 gather loads up front
    int2 w[4];
#pragma unroll
    for (int m = 0; m < 4; ++m) w[m] = *(const int2*)(row + 32 * m);

    float v[4][4];  // [m][k-slot]
#pragma unroll
    for (int m = 0; m < 4; ++m) {
        const float2 p0 = lut[w[m].x & 255];  // elements k=0,1 (h=1 fused)
        const float2 p1 = lut[w[m].y & 255];  // elements k=2,3
        // h=2 pairs (0,2) and (1,3):
        v[m][0] = p0.x + p1.x;
        v[m][2] = p0.x - p1.x;
        v[m][1] = p0.y + p1.y;
        v[m][3] = p0.y - p1.y;
    }

    const float s1 = (i & 1) ? -1.f : 1.f;
    const float s2 = (i & 2) ? -1.f : 1.f;
    const float s4 = (i & 4) ? -1.f : 1.f;
    const float s8 = (i & 8) ? -1.f : 1.f;

    // h=4: lane xor 1 (DPP quad_perm)
#pragma unroll
    for (int m = 0; m < 4; ++m)
#pragma unroll
        for (int k = 0; k < 4; ++k) v[m][k] = bfly_dpp<DPP_QUAD_XOR1>(v[m][k], s1);
    // h=8: lane xor 2 (DPP quad_perm)
#pragma unroll
    for (int m = 0; m < 4; ++m)
#pragma unroll
        for (int k = 0; k < 4; ++k) v[m][k] = bfly_dpp<DPP_QUAD_XOR2>(v[m][k], s2);
    // h=16: lane xor 4 (ds_swizzle — no DPP encoding for xor4)
#pragma unroll
    for (int m = 0; m < 4; ++m)
#pragma unroll
        for (int k = 0; k < 4; ++k) {
            const float o = __shfl_xor(v[m][k], 4);
            v[m][k] = fmaf(s4, v[m][k], o);
        }
    // h=32: lane xor 8 (DPP row_ror:8, partners stay within row-16)
#pragma unroll
    for (int m = 0; m < 4; ++m)
#pragma unroll
        for (int k = 0; k < 4; ++k) v[m][k] = bfly_dpp<DPP_ROW_ROR8>(v[m][k], s8);

    // in-register stages h=64 (m bit0), h=128 (m bit1)
#pragma unroll
    for (int k = 0; k < 4; ++k) {
        const float a = v[0][k], b = v[1][k], c = v[2][k], d = v[3][k];
        const float ab0 = a + b, ab1 = a - b, cd0 = c + d, cd1 = c - d;
        v[0][k] = ab0 + cd0;
        v[2][k] = ab0 - cd0;
        v[1][k] = ab1 + cd1;
        v[3][k] = ab1 - cd1;
    }

    const float    norm       = weight_norms[(size_t)id * 4 + g];
    const unsigned scale_bits = __float_as_uint(norm * (1.0f / 256.0f));  // norm>=0 -> bit31==0
    const unsigned u          = (unsigned)c_sign.u[g][i];                 // neg-flags, bit j=4m+k

    float* obase = out + (size_t)token * 1024 + g * 256 + 4 * i;
#pragma unroll
    for (int m = 0; m < 4; ++m) {
        float4 o;
        o.x = v[m][0] * __uint_as_float(((u << (31 - (4 * m + 0))) & 0x80000000u) ^ scale_bits);
        o.y = v[m][1] * __uint_as_float(((u << (31 - (4 * m + 1))) & 0x80000000u) ^ scale_bits);
        o.z = v[m][2] * __uint_as_float(((u << (31 - (4 * m + 2))) & 0x80000000u) ^ scale_bits);
        o.w = v[m][3] * __uint_as_float(((u << (31 - (4 * m + 3))) & 0x80000000u) ^ scale_bits);
        *(float4*)(obase + 64 * m) = o;  // 4x 256B dense segments per instr: coalesced
    }
}

extern "C" void kernel_launch(void* const* d_in, const int* in_sizes, int n_in,
                              void* d_out, int out_size, void* d_ws, size_t ws_size,
                              hipStream_t stream) {
    const int*   input_ids      = (const int*)d_in[0];
    const int*   indices_packed = (const int*)d_in[1];
    const float* weight_norms   = (const float*)d_in[2];
    const float* codebook       = (const float*)d_in[3];
    float*       out            = (float*)d_out;

    const int n_tokens = in_sizes[0];  // 8 * 4096 = 32768

    turboquant_kernel<<<(n_tokens + 3) / 4, 256, 0, stream>>>(
        input_ids, indices_packed, weight_norms, codebook, out, n_tokens);
}